// Round 3
// baseline (11783.381 us; speedup 1.0000x reference)
//
#include <hip/hip_runtime.h>

// ---------------- types / helpers ----------------
typedef short bhalf8 __attribute__((ext_vector_type(8)));   // 8 bf16 in 4 VGPRs
typedef float f32x4  __attribute__((ext_vector_type(4)));

__device__ __forceinline__ unsigned short f2bf(float f) {
    unsigned int u = __builtin_bit_cast(unsigned int, f);
    u = (u + 0x7fffu + ((u >> 16) & 1u)) >> 16;   // RNE
    return (unsigned short)u;
}
__device__ __forceinline__ float bf2f(unsigned short h) {
    unsigned int u = ((unsigned int)h) << 16;
    return __builtin_bit_cast(float, u);
}

#define SEQ   512
#define BATCH 64
#define HID   1024
#define EMBD  1024
#define VOCAB 32000
#define N3H   3072
#define NBLK  128

// ---------------- fp32 -> bf16 convert (4 elems/thread) ----------------
__global__ void k_cvt4(const float4* __restrict__ in, ushort4* __restrict__ out, int n4) {
    int i = blockIdx.x * blockDim.x + threadIdx.x;
    if (i < n4) {
        float4 v = in[i];
        ushort4 o;
        o.x = f2bf(v.x); o.y = f2bf(v.y); o.z = f2bf(v.z); o.w = f2bf(v.w);
        out[i] = o;
    }
}

// ---------------- gi GEMM: (32768 x 1024) gathered-A  @  W_ih^T -> bf16 ----------------
// block = 256 thr (4 waves). tile m64 x n64. wave = m16 x n64. no LDS (L2-fed).
__global__ __launch_bounds__(256)
void k_gi(const int* __restrict__ tok, const unsigned short* __restrict__ embb,
          const unsigned short* __restrict__ wih, unsigned short* __restrict__ gi) {
    int nb = blockIdx.x;            // 0..47
    int mb = blockIdx.y;            // 0..511
    int w    = threadIdx.x >> 6;
    int lane = threadIdx.x & 63;
    int q = lane >> 4, l = lane & 15;
    int m0 = mb * 64 + w * 16;
    int n0 = nb * 64;

    const unsigned short* arow = embb + (size_t)tok[m0 + l] * EMBD + q * 8;
    const unsigned short* b0 = wih + (size_t)(n0 + l) * EMBD + q * 8;
    const unsigned short* b1 = b0 + 16 * EMBD;
    const unsigned short* b2 = b0 + 32 * EMBD;
    const unsigned short* b3 = b0 + 48 * EMBD;

    f32x4 acc0 = {0.f, 0.f, 0.f, 0.f}, acc1 = acc0, acc2 = acc0, acc3 = acc0;

#pragma unroll 4
    for (int kk = 0; kk < 32; ++kk) {
        int ko = kk * 32;
        bhalf8 a = *(const bhalf8*)(arow + ko);
        acc0 = __builtin_amdgcn_mfma_f32_16x16x32_bf16(a, *(const bhalf8*)(b0 + ko), acc0, 0, 0, 0);
        acc1 = __builtin_amdgcn_mfma_f32_16x16x32_bf16(a, *(const bhalf8*)(b1 + ko), acc1, 0, 0, 0);
        acc2 = __builtin_amdgcn_mfma_f32_16x16x32_bf16(a, *(const bhalf8*)(b2 + ko), acc2, 0, 0, 0);
        acc3 = __builtin_amdgcn_mfma_f32_16x16x32_bf16(a, *(const bhalf8*)(b3 + ko), acc3, 0, 0, 0);
    }
    // C/D layout: row(m) = q*4+reg, col(n) = l
#pragma unroll
    for (int r = 0; r < 4; ++r) {
        size_t mrow = (size_t)(m0 + q * 4 + r) * N3H;
        gi[mrow + n0 +  0 + l] = f2bf(acc0[r]);
        gi[mrow + n0 + 16 + l] = f2bf(acc1[r]);
        gi[mrow + n0 + 32 + l] = f2bf(acc2[r]);
        gi[mrow + n0 + 48 + l] = f2bf(acc3[r]);
    }
}

// ---------------- device-scope epoch barrier ----------------
__device__ __forceinline__ void gbar(int* cnt, int e) {
    __threadfence();                 // release prior global stores (all threads)
    __syncthreads();
    if (threadIdx.x == 0) {
        __hip_atomic_fetch_add(cnt + e, 1, __ATOMIC_ACQ_REL, __HIP_MEMORY_SCOPE_AGENT);
        while (__hip_atomic_load(cnt + e, __ATOMIC_ACQUIRE, __HIP_MEMORY_SCOPE_AGENT) < NBLK)
            __builtin_amdgcn_s_sleep(2);
    }
    __syncthreads();
    __threadfence();                 // acquire: invalidate for fresh reads
}

// ---------------- persistent recurrence ----------------
// 128 blocks = 64 unit-groups x 2 batch-halves. block = 128 thr (2 waves, 16 batches each).
// W_hh r/z gate fragments in LDS (64 KB, MFMA-fragment order, conflict-free b128 reads);
// n-gate fragments in registers (32 x bhalf8 = 128 VGPR). h_prev fp32 lives in registers.
__global__ __launch_bounds__(128, 1)
void k_rec(const float* __restrict__ W_hh,
           const unsigned short* __restrict__ gib,
           const float* __restrict__ bih, const float* __restrict__ bhh,
           const float* __restrict__ hidden,
           float* __restrict__ out,
           unsigned short* hbuf,          // bf16 [2][64*1024]
           int* cnt) {                    // [SEQ+1], zeroed
    __shared__ unsigned short sh[32768];  // 64 KB: gates r,z

    const int tid  = threadIdx.x;
    const int w    = tid >> 6;
    const int lane = tid & 63;
    const int q = lane >> 4, l = lane & 15;
    const int G  = blockIdx.x >> 1;       // unit group 0..63
    const int mh = blockIdx.x & 1;
    const int m0 = mh * 32 + w * 16;
    const int u0 = G * 16 + l;

    // ---- prologue: r,z gate fragments -> LDS (fragment order: [g][kk][lane]*16B) ----
    for (int i = 0; i < 32; ++i) {
        int c  = i * 128 + tid;           // 0..4095
        int g  = c >> 11;                 // 0..1
        int kk = (c >> 6) & 31;
        int ln = c & 63;
        int uu = ln & 15, qq = ln >> 4;
        const float* src = W_hh + (size_t)(g * 1024 + G * 16 + uu) * 1024 + kk * 32 + qq * 8;
        float4 f0 = *(const float4*)src;
        float4 f1 = *(const float4*)(src + 4);
        ushort4 o0, o1;
        o0.x = f2bf(f0.x); o0.y = f2bf(f0.y); o0.z = f2bf(f0.z); o0.w = f2bf(f0.w);
        o1.x = f2bf(f1.x); o1.y = f2bf(f1.y); o1.z = f2bf(f1.z); o1.w = f2bf(f1.w);
        *(ushort4*)&sh[c * 8]     = o0;
        *(ushort4*)&sh[c * 8 + 4] = o1;
    }

    // ---- n-gate fragments in registers: B[n=l][k=q*8+j], col = kk*32+q*8+j ----
    bhalf8 bn[32];
#pragma unroll
    for (int kk = 0; kk < 32; ++kk) {
        const float* src = W_hh + (size_t)(2048 + u0) * 1024 + kk * 32 + q * 8;
        float4 f0 = *(const float4*)src;
        float4 f1 = *(const float4*)(src + 4);
        bhalf8 v;
        v[0] = (short)f2bf(f0.x); v[1] = (short)f2bf(f0.y);
        v[2] = (short)f2bf(f0.z); v[3] = (short)f2bf(f0.w);
        v[4] = (short)f2bf(f1.x); v[5] = (short)f2bf(f1.y);
        v[6] = (short)f2bf(f1.z); v[7] = (short)f2bf(f1.w);
        bn[kk] = v;
    }

    // ---- h0 init: own slice into hbuf[0] + hp registers; biases ----
    float hp[4];
#pragma unroll
    for (int r = 0; r < 4; ++r) {
        int b = m0 + q * 4 + r;
        float hv = hidden[(size_t)b * HID + u0];
        hp[r] = hv;
        hbuf[(size_t)b * HID + u0] = f2bf(hv);
    }
    float bir = bih[u0], biz = bih[HID + u0], bin = bih[2 * HID + u0];
    float bhr = bhh[u0], bhz = bhh[HID + u0], bhn = bhh[2 * HID + u0];

    gbar(cnt, 0);   // h0 visible everywhere; also covers LDS fill

    for (int t = 0; t < SEQ; ++t) {
        const unsigned short* hc = hbuf + (size_t)(t & 1) * (BATCH * HID);
        unsigned short*       hn = hbuf + (size_t)((t + 1) & 1) * (BATCH * HID);
        const unsigned short* gt = gib + (size_t)t * (BATCH * N3H);

        // gi prefetch (independent of h) — b_ih folded in HERE (R2 bug: was missing)
        float i_r[4], i_z[4], i_n[4];
#pragma unroll
        for (int r = 0; r < 4; ++r) {
            const unsigned short* gp = gt + (size_t)(m0 + q * 4 + r) * N3H + u0;
            i_r[r] = bf2f(gp[0])       + bir;
            i_z[r] = bf2f(gp[HID])     + biz;
            i_n[r] = bf2f(gp[2 * HID]) + bin;
        }

        const unsigned short* hA = hc + (size_t)(m0 + l) * HID + q * 8;
        f32x4 ar = {0.f, 0.f, 0.f, 0.f}, az = ar, an = ar;
#pragma unroll
        for (int kk = 0; kk < 32; ++kk) {
            bhalf8 a   = *(const bhalf8*)(hA + kk * 32);
            bhalf8 brf = *(const bhalf8*)&sh[kk * 512 + lane * 8];
            bhalf8 bzf = *(const bhalf8*)&sh[16384 + kk * 512 + lane * 8];
            ar = __builtin_amdgcn_mfma_f32_16x16x32_bf16(a, brf, ar, 0, 0, 0);
            az = __builtin_amdgcn_mfma_f32_16x16x32_bf16(a, bzf, az, 0, 0, 0);
            an = __builtin_amdgcn_mfma_f32_16x16x32_bf16(a, bn[kk], an, 0, 0, 0);
        }

        float* ot = out + (size_t)t * (BATCH * HID);
#pragma unroll
        for (int r = 0; r < 4; ++r) {
            int b = m0 + q * 4 + r;
            float rr = 1.f / (1.f + __expf(-(i_r[r] + ar[r] + bhr)));
            float zz = 1.f / (1.f + __expf(-(i_z[r] + az[r] + bhz)));
            float nn = tanhf(i_n[r] + rr * (an[r] + bhn));
            float hv = (1.f - zz) * nn + zz * hp[r];
            hp[r] = hv;
            ot[(size_t)b * HID + u0] = hv;
            hn[(size_t)b * HID + u0] = f2bf(hv);
        }
        gbar(cnt, t + 1);
    }
}

// ---------------- launch ----------------
extern "C" void kernel_launch(void* const* d_in, const int* in_sizes, int n_in,
                              void* d_out, int out_size, void* d_ws, size_t ws_size,
                              hipStream_t stream) {
    (void)in_sizes; (void)n_in; (void)out_size;
    const int*   input  = (const int*)  d_in[0];
    const float* hidden = (const float*)d_in[2];
    const float* emb    = (const float*)d_in[3];
    const float* W_ih   = (const float*)d_in[4];
    const float* W_hh   = (const float*)d_in[5];
    const float* b_ih   = (const float*)d_in[6];
    const float* b_hh   = (const float*)d_in[7];
    float* out = (float*)d_out;

    // workspace layout (bytes)
    const size_t EMB_BF  = 0;                                   // 65,536,000
    const size_t WIH_BF  = EMB_BF + (size_t)VOCAB * EMBD * 2;   // +6,291,456
    const size_t GI_OFF  = WIH_BF + (size_t)N3H * EMBD * 2;     // +201,326,592
    const size_t H_OFF   = GI_OFF + (size_t)SEQ * BATCH * N3H * 2;
    const size_t CNT_OFF = H_OFF + (size_t)2 * BATCH * HID * 2;
    const size_t NEED    = CNT_OFF + (size_t)(SEQ + 1) * 4;
    if (ws_size < NEED) return;

    char* ws = (char*)d_ws;
    unsigned short* embb = (unsigned short*)(ws + EMB_BF);
    unsigned short* wihb = (unsigned short*)(ws + WIH_BF);
    unsigned short* gib  = (unsigned short*)(ws + GI_OFF);
    unsigned short* hbuf = (unsigned short*)(ws + H_OFF);
    int*            cnt  = (int*)(ws + CNT_OFF);

    hipMemsetAsync(cnt, 0, (size_t)(SEQ + 1) * 4, stream);

    {
        int n4 = VOCAB * EMBD / 4;
        k_cvt4<<<(n4 + 255) / 256, 256, 0, stream>>>((const float4*)emb, (ushort4*)embb, n4);
    }
    {
        int n4 = N3H * EMBD / 4;
        k_cvt4<<<(n4 + 255) / 256, 256, 0, stream>>>((const float4*)W_ih, (ushort4*)wihb, n4);
    }

    // input-side GEMM for all timesteps
    k_gi<<<dim3(48, 512), 256, 0, stream>>>(input, embb, wihb, gib);

    // persistent recurrence: 128 blocks (64 KB LDS each -> all co-resident on 256 CUs)
    k_rec<<<NBLK, 128, 0, stream>>>(W_hh, gib, b_ih, b_hh, hidden, out, hbuf, cnt);
}

// Round 4
// 7043.610 us; speedup vs baseline: 1.6729x; 1.6729x over previous
//
#include <hip/hip_runtime.h>

// ---------------- types / helpers ----------------
typedef short bhalf8 __attribute__((ext_vector_type(8)));   // 8 bf16 in 4 VGPRs
typedef float f32x4  __attribute__((ext_vector_type(4)));

__device__ __forceinline__ unsigned short f2bf(float f) {
    unsigned int u = __builtin_bit_cast(unsigned int, f);
    u = (u + 0x7fffu + ((u >> 16) & 1u)) >> 16;   // RNE
    return (unsigned short)u;
}
__device__ __forceinline__ float bf2f(unsigned short h) {
    unsigned int u = ((unsigned int)h) << 16;
    return __builtin_bit_cast(float, u);
}

#define SEQ   512
#define BATCH 64
#define HID   1024
#define EMBD  1024
#define VOCAB 32000
#define N3H   3072
#define NBLK  128

// ---------------- fp32 -> bf16 convert (4 elems/thread) ----------------
__global__ void k_cvt4(const float4* __restrict__ in, ushort4* __restrict__ out, int n4) {
    int i = blockIdx.x * blockDim.x + threadIdx.x;
    if (i < n4) {
        float4 v = in[i];
        ushort4 o;
        o.x = f2bf(v.x); o.y = f2bf(v.y); o.z = f2bf(v.z); o.w = f2bf(v.w);
        out[i] = o;
    }
}

// ---------------- gi GEMM: (32768 x 1024) gathered-A  @  W_ih^T -> bf16 ----------------
// block = 256 thr (4 waves). wave tile = m(4x16) x n64: 16 accs, B-frags reused 4x.
__global__ __launch_bounds__(256)
void k_gi(const int* __restrict__ tok, const unsigned short* __restrict__ embb,
          const unsigned short* __restrict__ wih, unsigned short* __restrict__ gi) {
    int nb = blockIdx.x;            // 0..47
    int mb = blockIdx.y;            // 0..127
    int w    = threadIdx.x >> 6;
    int lane = threadIdx.x & 63;
    int q = lane >> 4, l = lane & 15;
    int m0 = mb * 256 + w * 16;     // m-tiles at m0 + 64*i, i=0..3
    int n0 = nb * 64;

    const unsigned short* ap[4];
#pragma unroll
    for (int i = 0; i < 4; ++i)
        ap[i] = embb + (size_t)tok[m0 + 64 * i + l] * EMBD + q * 8;

    const unsigned short* bp[4];
#pragma unroll
    for (int j = 0; j < 4; ++j)
        bp[j] = wih + (size_t)(n0 + 16 * j + l) * EMBD + q * 8;

    f32x4 acc[4][4];
#pragma unroll
    for (int i = 0; i < 4; ++i)
#pragma unroll
        for (int j = 0; j < 4; ++j)
            acc[i][j] = (f32x4){0.f, 0.f, 0.f, 0.f};

#pragma unroll 2
    for (int kk = 0; kk < 32; ++kk) {
        int ko = kk * 32;
        bhalf8 bv[4], av[4];
#pragma unroll
        for (int j = 0; j < 4; ++j) bv[j] = *(const bhalf8*)(bp[j] + ko);
#pragma unroll
        for (int i = 0; i < 4; ++i) av[i] = *(const bhalf8*)(ap[i] + ko);
#pragma unroll
        for (int i = 0; i < 4; ++i)
#pragma unroll
            for (int j = 0; j < 4; ++j)
                acc[i][j] = __builtin_amdgcn_mfma_f32_16x16x32_bf16(av[i], bv[j], acc[i][j], 0, 0, 0);
    }
    // C/D layout: row(m) = q*4+reg, col(n) = l
#pragma unroll
    for (int i = 0; i < 4; ++i)
#pragma unroll
        for (int r = 0; r < 4; ++r) {
            size_t mrow = (size_t)(m0 + 64 * i + q * 4 + r) * N3H + n0;
            gi[mrow +  0 + l] = f2bf(acc[i][0][r]);
            gi[mrow + 16 + l] = f2bf(acc[i][1][r]);
            gi[mrow + 32 + l] = f2bf(acc[i][2][r]);
            gi[mrow + 48 + l] = f2bf(acc[i][3][r]);
        }
}

// ---------------- device-scope epoch barrier (minimal coherence ops) ----------------
// arrive: one RELEASE add (waitcnt + wbl2, no inv). spin: RELAXED loads (no cache ops).
// depart: one ACQUIRE load per wave (single buffer_inv), ordered before subsequent loads.
__device__ __forceinline__ void gbar(int* cnt, int e) {
    __syncthreads();   // compiler drains vmcnt before s_barrier -> all block stores in L2
    if (threadIdx.x == 0) {
        __hip_atomic_fetch_add(cnt + e, 1, __ATOMIC_RELEASE, __HIP_MEMORY_SCOPE_AGENT);
        while (__hip_atomic_load(cnt + e, __ATOMIC_RELAXED, __HIP_MEMORY_SCOPE_AGENT) < NBLK)
            __builtin_amdgcn_s_sleep(2);
    }
    __syncthreads();
    int v = __hip_atomic_load(cnt + e, __ATOMIC_ACQUIRE, __HIP_MEMORY_SCOPE_AGENT);
    if (v < NBLK) __builtin_amdgcn_s_sleep(1);   // never taken; keeps the load alive
}

// ---------------- persistent recurrence ----------------
// 128 blocks = 64 unit-groups x 2 batch-halves. block = 128 thr (2 waves, 16 batches each).
__global__ __launch_bounds__(128, 1)
void k_rec(const float* __restrict__ W_hh,
           const unsigned short* __restrict__ gib,
           const float* __restrict__ bih, const float* __restrict__ bhh,
           const float* __restrict__ hidden,
           float* __restrict__ out,
           unsigned short* hbuf,          // bf16 [2][64*1024]
           int* cnt) {                    // [SEQ+1], zeroed
    __shared__ unsigned short sh[32768];  // 64 KB: gates r,z

    const int tid  = threadIdx.x;
    const int w    = tid >> 6;
    const int lane = tid & 63;
    const int q = lane >> 4, l = lane & 15;
    const int G  = blockIdx.x >> 1;       // unit group 0..63
    const int mh = blockIdx.x & 1;
    const int m0 = mh * 32 + w * 16;
    const int u0 = G * 16 + l;

    // ---- prologue: r,z gate fragments -> LDS (fragment order: [g][kk][lane]*16B) ----
    for (int i = 0; i < 32; ++i) {
        int c  = i * 128 + tid;           // 0..4095
        int g  = c >> 11;                 // 0..1
        int kk = (c >> 6) & 31;
        int ln = c & 63;
        int uu = ln & 15, qq = ln >> 4;
        const float* src = W_hh + (size_t)(g * 1024 + G * 16 + uu) * 1024 + kk * 32 + qq * 8;
        float4 f0 = *(const float4*)src;
        float4 f1 = *(const float4*)(src + 4);
        ushort4 o0, o1;
        o0.x = f2bf(f0.x); o0.y = f2bf(f0.y); o0.z = f2bf(f0.z); o0.w = f2bf(f0.w);
        o1.x = f2bf(f1.x); o1.y = f2bf(f1.y); o1.z = f2bf(f1.z); o1.w = f2bf(f1.w);
        *(ushort4*)&sh[c * 8]     = o0;
        *(ushort4*)&sh[c * 8 + 4] = o1;
    }

    // ---- n-gate fragments in registers ----
    bhalf8 bn[32];
#pragma unroll
    for (int kk = 0; kk < 32; ++kk) {
        const float* src = W_hh + (size_t)(2048 + u0) * 1024 + kk * 32 + q * 8;
        float4 f0 = *(const float4*)src;
        float4 f1 = *(const float4*)(src + 4);
        bhalf8 v;
        v[0] = (short)f2bf(f0.x); v[1] = (short)f2bf(f0.y);
        v[2] = (short)f2bf(f0.z); v[3] = (short)f2bf(f0.w);
        v[4] = (short)f2bf(f1.x); v[5] = (short)f2bf(f1.y);
        v[6] = (short)f2bf(f1.z); v[7] = (short)f2bf(f1.w);
        bn[kk] = v;
    }

    // ---- h0 init + biases ----
    float hp[4];
#pragma unroll
    for (int r = 0; r < 4; ++r) {
        int b = m0 + q * 4 + r;
        float hv = hidden[(size_t)b * HID + u0];
        hp[r] = hv;
        hbuf[(size_t)b * HID + u0] = f2bf(hv);
    }
    float bir = bih[u0], biz = bih[HID + u0], bin = bih[2 * HID + u0];
    float bhr = bhh[u0], bhz = bhh[HID + u0], bhn = bhh[2 * HID + u0];

    // ---- gi prefetch for t=0 (b_ih folded in) ----
    float i_r[4], i_z[4], i_n[4];
#pragma unroll
    for (int r = 0; r < 4; ++r) {
        const unsigned short* gp = gib + (size_t)(m0 + q * 4 + r) * N3H + u0;
        i_r[r] = bf2f(gp[0])       + bir;
        i_z[r] = bf2f(gp[HID])     + biz;
        i_n[r] = bf2f(gp[2 * HID]) + bin;
    }

    gbar(cnt, 0);   // h0 + LDS fill visible

    for (int t = 0; t < SEQ; ++t) {
        const unsigned short* hc = hbuf + (size_t)(t & 1) * (BATCH * HID);
        unsigned short*       hn = hbuf + (size_t)((t + 1) & 1) * (BATCH * HID);

        const unsigned short* hA = hc + (size_t)(m0 + l) * HID + q * 8;
        f32x4 ar = {0.f, 0.f, 0.f, 0.f}, az = ar, an = ar;
#pragma unroll
        for (int kk = 0; kk < 32; ++kk) {
            bhalf8 a   = *(const bhalf8*)(hA + kk * 32);
            bhalf8 brf = *(const bhalf8*)&sh[kk * 512 + lane * 8];
            bhalf8 bzf = *(const bhalf8*)&sh[16384 + kk * 512 + lane * 8];
            ar = __builtin_amdgcn_mfma_f32_16x16x32_bf16(a, brf, ar, 0, 0, 0);
            az = __builtin_amdgcn_mfma_f32_16x16x32_bf16(a, bzf, az, 0, 0, 0);
            an = __builtin_amdgcn_mfma_f32_16x16x32_bf16(a, bn[kk], an, 0, 0, 0);
        }

        float* ot = out + (size_t)t * (BATCH * HID);
#pragma unroll
        for (int r = 0; r < 4; ++r) {
            int b = m0 + q * 4 + r;
            float rr = 1.f / (1.f + __expf(-(i_r[r] + ar[r] + bhr)));
            float zz = 1.f / (1.f + __expf(-(i_z[r] + az[r] + bhz)));
            float nn = tanhf(i_n[r] + rr * (an[r] + bhn));
            float hv = (1.f - zz) * nn + zz * hp[r];
            hp[r] = hv;
            __builtin_nontemporal_store(hv, &ot[(size_t)b * HID + u0]);  // never re-read; keep L2 clean
            hn[(size_t)b * HID + u0] = f2bf(hv);
        }

        // prefetch gi(t+1) BEFORE the barrier — latency hides under the wait
        if (t + 1 < SEQ) {
            const unsigned short* gt = gib + (size_t)(t + 1) * (BATCH * N3H);
#pragma unroll
            for (int r = 0; r < 4; ++r) {
                const unsigned short* gp = gt + (size_t)(m0 + q * 4 + r) * N3H + u0;
                i_r[r] = bf2f(gp[0])       + bir;
                i_z[r] = bf2f(gp[HID])     + biz;
                i_n[r] = bf2f(gp[2 * HID]) + bin;
            }
            gbar(cnt, t + 1);
        }
    }
}

// ---------------- launch ----------------
extern "C" void kernel_launch(void* const* d_in, const int* in_sizes, int n_in,
                              void* d_out, int out_size, void* d_ws, size_t ws_size,
                              hipStream_t stream) {
    (void)in_sizes; (void)n_in; (void)out_size;
    const int*   input  = (const int*)  d_in[0];
    const float* hidden = (const float*)d_in[2];
    const float* emb    = (const float*)d_in[3];
    const float* W_ih   = (const float*)d_in[4];
    const float* W_hh   = (const float*)d_in[5];
    const float* b_ih   = (const float*)d_in[6];
    const float* b_hh   = (const float*)d_in[7];
    float* out = (float*)d_out;

    // workspace layout (bytes)
    const size_t EMB_BF  = 0;                                   // 65,536,000
    const size_t WIH_BF  = EMB_BF + (size_t)VOCAB * EMBD * 2;   // +6,291,456
    const size_t GI_OFF  = WIH_BF + (size_t)N3H * EMBD * 2;     // +201,326,592
    const size_t H_OFF   = GI_OFF + (size_t)SEQ * BATCH * N3H * 2;
    const size_t CNT_OFF = H_OFF + (size_t)2 * BATCH * HID * 2;
    const size_t NEED    = CNT_OFF + (size_t)(SEQ + 1) * 4;
    if (ws_size < NEED) return;

    char* ws = (char*)d_ws;
    unsigned short* embb = (unsigned short*)(ws + EMB_BF);
    unsigned short* wihb = (unsigned short*)(ws + WIH_BF);
    unsigned short* gib  = (unsigned short*)(ws + GI_OFF);
    unsigned short* hbuf = (unsigned short*)(ws + H_OFF);
    int*            cnt  = (int*)(ws + CNT_OFF);

    hipMemsetAsync(cnt, 0, (size_t)(SEQ + 1) * 4, stream);

    {
        int n4 = VOCAB * EMBD / 4;
        k_cvt4<<<(n4 + 255) / 256, 256, 0, stream>>>((const float4*)emb, (ushort4*)embb, n4);
    }
    {
        int n4 = N3H * EMBD / 4;
        k_cvt4<<<(n4 + 255) / 256, 256, 0, stream>>>((const float4*)W_ih, (ushort4*)wihb, n4);
    }

    // input-side GEMM for all timesteps
    k_gi<<<dim3(48, 128), 256, 0, stream>>>(input, embb, wihb, gib);

    // persistent recurrence: 128 blocks (64 KB LDS each -> all co-resident)
    k_rec<<<NBLK, 128, 0, stream>>>(W_hh, gib, b_ih, b_hh, hidden, out, hbuf, cnt);
}